// Round 1
// baseline (192.188 us; speedup 1.0000x reference)
//
#include <hip/hip_runtime.h>
#include <hip/hip_cooperative_groups.h>
#include <stdint.h>

namespace cg = cooperative_groups;

#define NBOX 8192
#define NW   128            // NBOX/64 words
#define IOU_THR 0.45f

// ---------------- K0: re-init workspace state every call ----------------
__global__ void k_init(int* flags, int* rank1, int* rank2, unsigned long long* keptA) {
    int t = blockIdx.x * blockDim.x + threadIdx.x;
    if (t < NBOX) { flags[t] = 0; rank1[t] = 0; rank2[t] = 0; }
    if (t < NW) keptA[t] = ~0ULL;   // initial: nothing suppressed
}

// ---------------- K1: max over all 4N coords, store max+1 ----------------
__global__ void k_max(const float* __restrict__ boxes, float* maxc1) {
    __shared__ float red[256];
    float m = 0.0f;                       // all coords >= 0
    for (int i = threadIdx.x; i < NBOX * 4; i += 256) m = fmaxf(m, boxes[i]);
    red[threadIdx.x] = m;
    __syncthreads();
    for (int s = 128; s > 0; s >>= 1) {
        if (threadIdx.x < s) red[threadIdx.x] = fmaxf(red[threadIdx.x], red[threadIdx.x + s]);
        __syncthreads();
    }
    if (threadIdx.x == 0) *maxc1 = red[0] + 1.0f;
}

// ---------------- K2: sort key = (~bits(score))<<32 | idx  (ascending == score desc, idx asc) ----------------
__global__ void k_key1(const float* __restrict__ scores, unsigned long long* __restrict__ key1) {
    int j = blockIdx.x * 256 + threadIdx.x;
    if (j >= NBOX) return;
    uint32_t u = ~__float_as_uint(scores[j]);
    key1[j] = ((unsigned long long)u << 32) | (unsigned)j;
}

// ---------------- rank-count sort: rank[j] = #{i : key[i] < key[j]} ----------------
// grid = 256 blocks: 32 j-chunks x 8 i-parts (1024 keys each)
__global__ void k_rank(const unsigned long long* __restrict__ key, int* __restrict__ rank) {
    __shared__ unsigned long long lk[1024];
    int jc = blockIdx.x & 31;
    int ip = blockIdx.x >> 5;
    int base = ip * 1024;
    for (int i = threadIdx.x; i < 1024; i += 256) lk[i] = key[base + i];
    __syncthreads();
    int j = jc * 256 + threadIdx.x;
    unsigned long long kj = key[j];
    int cnt = 0;
#pragma unroll 8
    for (int i = 0; i < 1024; ++i) cnt += (lk[i] < kj) ? 1 : 0;
    atomicAdd(&rank[j], cnt);
}

__global__ void k_scatter(const int* __restrict__ rank, int* __restrict__ pos) {
    int j = blockIdx.x * 256 + threadIdx.x;
    if (j < NBOX) pos[rank[j]] = j;
}

// ---------------- K4: gather boxes in sorted order, apply class offsets, areas ----------------
__global__ void k_gather(const float4* __restrict__ boxes4, const int* __restrict__ idxs,
                         const int* __restrict__ order, const float* __restrict__ maxc1,
                         float4* __restrict__ sb, float* __restrict__ area) {
    int r = blockIdx.x * 256 + threadIdx.x;
    if (r >= NBOX) return;
    int j = order[r];
    float4 b = boxes4[j];
    float off = (float)idxs[j] * (*maxc1);
    b.x += off; b.y += off; b.z += off; b.w += off;
    sb[r] = b;
    area[r] = (b.z - b.x) * (b.w - b.y);
}

// ---------------- K5: overlap mask, transposed: OV[w*NBOX + j] bit b = over(i=64w+b, j) && i<j ----------------
__global__ void k_mask(const float4* __restrict__ sb, const float* __restrict__ area,
                       unsigned long long* __restrict__ OV) {
    __shared__ float4 ib[64];
    __shared__ float  ia[64];
    int w = blockIdx.x;                       // 0..127
    int j = blockIdx.y * 256 + threadIdx.x;   // 0..8191
    if (threadIdx.x < 64) {
        ib[threadIdx.x] = sb[w * 64 + threadIdx.x];
        ia[threadIdx.x] = area[w * 64 + threadIdx.x];
    }
    __syncthreads();
    unsigned long long word = 0;
    if (w * 64 < j) {                         // some i<j exists in this word
        float4 bj = sb[j];
        float  aj = area[j];
        int nb = min(64, j - w * 64);
        for (int b = 0; b < nb; ++b) {
            float4 bi = ib[b];
            float ltx = fmaxf(bi.x, bj.x), lty = fmaxf(bi.y, bj.y);
            float rbx = fminf(bi.z, bj.z), rby = fminf(bi.w, bj.w);
            float wx = fmaxf(rbx - ltx, 0.0f), wy = fmaxf(rby - lty, 0.0f);
            float inter = wx * wy;
            if (inter > 0.0f) {               // zero-intersection => iou==0, never over
                float iou = inter / (ia[b] + aj - inter);   // IEEE f32 div, matches ref
                if (iou > IOU_THR) word |= (1ULL << b);
            }
        }
    }
    OV[(size_t)w * NBOX + j] = word;
}

// ---------------- K6: cooperative fixpoint of the greedy-NMS recursion ----------------
// kept bit r (sorted order). S' [j] = OR_w ( OV[w][j] & kept[w] );  kept'[j] = !S'[j]
__global__ void __launch_bounds__(512, 1)
k_fix(const unsigned long long* __restrict__ OV,
      unsigned long long* keptA, unsigned long long* keptB,
      unsigned long long* keptFinal, int* flags) {
    cg::grid_group grid = cg::this_grid();
    __shared__ unsigned long long keptLDS[NW];
    __shared__ unsigned long long part[8][64];
    __shared__ int chg;

    const int t  = threadIdx.x;
    const int jl = t & 63;       // lane within word
    const int c  = t >> 6;       // wave / i-chunk (0..7)
    const int b  = blockIdx.x;   // this block owns output word b (64 j's)
    const int j  = b * 64 + jl;

    unsigned long long* bufs[2] = { keptA, keptB };
    int cur = 0;

    for (int iter = 0; iter < NBOX; ++iter) {
        if (t < NW) keptLDS[t] = bufs[cur][t];
        __syncthreads();

        unsigned long long acc = 0;
#pragma unroll
        for (int ww = 0; ww < 16; ++ww) {
            int w = c * 16 + ww;
            acc |= OV[(size_t)w * NBOX + j] & keptLDS[w];
        }
        part[c][jl] = acc;
        __syncthreads();

        if (c == 0) {
            unsigned long long sup = part[0][jl] | part[1][jl] | part[2][jl] | part[3][jl]
                                   | part[4][jl] | part[5][jl] | part[6][jl] | part[7][jl];
            unsigned long long newW = __ballot(sup == 0ULL);   // kept = not suppressed
            if (jl == 0) {
                bufs[cur ^ 1][b] = newW;
                if (newW != keptLDS[b]) atomicOr(&flags[iter], 1);
            }
        }
        __threadfence();
        grid.sync();

        if (t == 0) chg = atomicOr(&flags[iter], 0);   // coherent read
        __syncthreads();
        cur ^= 1;
        if (!chg) break;        // newly written buffer == old buffer == fixpoint
    }
    if (t == 0) keptFinal[b] = bufs[cur][b];
}

// ---------------- K7: map kept back to original order; key2 for final stable sort ----------------
__global__ void k_key2(const int* __restrict__ order, const unsigned long long* __restrict__ keptFinal,
                       const float* __restrict__ scores, float* __restrict__ sa,
                       unsigned long long* __restrict__ key2) {
    int r = blockIdx.x * 256 + threadIdx.x;
    if (r >= NBOX) return;
    int j = order[r];
    int k = (int)((keptFinal[r >> 6] >> (r & 63)) & 1ULL);
    float s = k ? scores[j] : 0.0f;
    sa[j] = s;
    uint32_t u = ~__float_as_uint(s);
    key2[j] = ((unsigned long long)u << 32) | (unsigned)j;
}

// ---------------- K9: final output: [N,5] boxes+score, then N inds (as float) ----------------
__global__ void k_out(const float4* __restrict__ boxes4, const float* __restrict__ sa,
                      const int* __restrict__ inds, float* __restrict__ out) {
    int r = blockIdx.x * 256 + threadIdx.x;
    if (r >= NBOX) return;
    int j = inds[r];
    float4 bx = boxes4[j];
    out[r * 5 + 0] = bx.x;
    out[r * 5 + 1] = bx.y;
    out[r * 5 + 2] = bx.z;
    out[r * 5 + 3] = bx.w;
    out[r * 5 + 4] = sa[j];
    out[NBOX * 5 + r] = (float)j;
}

extern "C" void kernel_launch(void* const* d_in, const int* in_sizes, int n_in,
                              void* d_out, int out_size, void* d_ws, size_t ws_size,
                              hipStream_t stream) {
    const float* boxes  = (const float*)d_in[0];
    const float* scores = (const float*)d_in[1];
    const int*   idxs   = (const int*)d_in[2];
    float* out = (float*)d_out;

    char* w = (char*)d_ws;
    float4* sb                  = (float4*)(w + 0);                 // 131072
    float*  area                = (float*) (w + 131072);            // 32768
    unsigned long long* OV      = (unsigned long long*)(w + 163840);   // 8388608
    unsigned long long* key1    = (unsigned long long*)(w + 8552448);  // 65536
    unsigned long long* key2    = (unsigned long long*)(w + 8617984);  // 65536
    unsigned long long* keptA   = (unsigned long long*)(w + 8683520);  // 1024
    unsigned long long* keptB   = (unsigned long long*)(w + 8684544);  // 1024
    unsigned long long* keptF   = (unsigned long long*)(w + 8685568);  // 1024
    int*    rank1               = (int*)   (w + 8686592);           // 32768
    int*    rank2               = (int*)   (w + 8719360);           // 32768
    int*    order               = (int*)   (w + 8752128);           // 32768
    int*    inds                = (int*)   (w + 8784896);           // 32768
    int*    flags               = (int*)   (w + 8817664);           // 32768
    float*  sa                  = (float*) (w + 8850432);           // 32768
    float*  maxc1               = (float*) (w + 8883200);           // 4

    k_init<<<32, 256, 0, stream>>>(flags, rank1, rank2, keptA);
    k_max<<<1, 256, 0, stream>>>(boxes, maxc1);
    k_key1<<<32, 256, 0, stream>>>(scores, key1);
    k_rank<<<256, 256, 0, stream>>>(key1, rank1);
    k_scatter<<<32, 256, 0, stream>>>(rank1, order);
    k_gather<<<32, 256, 0, stream>>>((const float4*)boxes, idxs, order, maxc1, sb, area);
    dim3 gm(128, 32);
    k_mask<<<gm, 256, 0, stream>>>(sb, area, OV);

    {
        const unsigned long long* ovc = OV;
        void* args[] = { (void*)&ovc, (void*)&keptA, (void*)&keptB, (void*)&keptF, (void*)&flags };
        hipLaunchCooperativeKernel((void*)k_fix, dim3(128), dim3(512), args, 0, stream);
    }

    k_key2<<<32, 256, 0, stream>>>(order, keptF, scores, sa, key2);
    k_rank<<<256, 256, 0, stream>>>(key2, rank2);
    k_scatter<<<32, 256, 0, stream>>>(rank2, inds);
    k_out<<<32, 256, 0, stream>>>((const float4*)boxes, sa, inds, out);
}

// Round 2
// 99.567 us; speedup vs baseline: 1.9302x; 1.9302x over previous
//
#include <hip/hip_runtime.h>
#include <stdint.h>

#define NBOX 8192
#define NW   128            // NBOX/64 words
#define IOU_THR 0.45f
#define ENT_CAP 65536u      // global entry capacity
#define ENT_LDS 2560        // LDS-staged entry capacity (40 KB)

typedef unsigned long long u64;
typedef unsigned int u32;

// ---------------- K1: init state + sort key1 (fused) ----------------
// key = (~bits(score))<<32 | idx : ascending == (score desc, idx asc) == stable argsort(-scores)
__global__ void k_init(const float* __restrict__ scores, u64* __restrict__ key1,
                       int* __restrict__ rank1, u32* __restrict__ cursor, u32* __restrict__ maxc) {
    int j = blockIdx.x * 256 + threadIdx.x;
    if (j < NBOX) {
        rank1[j] = 0;
        u32 u = ~__float_as_uint(scores[j]);
        key1[j] = ((u64)u << 32) | (u32)j;
    }
    if (j == 0) { *cursor = 0u; *maxc = 0u; }
}

// ---------------- K2: grid-parallel max(boxes) via uint atomicMax (coords >= 0) ----------------
__global__ void k_max(const float* __restrict__ boxes, u32* __restrict__ maxc) {
    __shared__ float red[256];
    float m = 0.0f;
    for (int i = blockIdx.x * 256 + threadIdx.x; i < NBOX * 4; i += 32 * 256)
        m = fmaxf(m, boxes[i]);
    red[threadIdx.x] = m;
    __syncthreads();
    for (int s = 128; s > 0; s >>= 1) {
        if (threadIdx.x < s) red[threadIdx.x] = fmaxf(red[threadIdx.x], red[threadIdx.x + s]);
        __syncthreads();
    }
    if (threadIdx.x == 0) atomicMax(maxc, __float_as_uint(red[0]));
}

// ---------------- K3: rank-count sort: rank[j] += #{i in part : key[i] < key[j]} ----------------
__global__ void k_rank(const u64* __restrict__ key, int* __restrict__ rank) {
    __shared__ u64 lk[1024];
    int jc = blockIdx.x & 31;
    int ip = blockIdx.x >> 5;
    int base = ip * 1024;
    for (int i = threadIdx.x; i < 1024; i += 256) lk[i] = key[base + i];
    __syncthreads();
    int j = jc * 256 + threadIdx.x;
    u64 kj = key[j];
    int cnt = 0;
#pragma unroll 8
    for (int i = 0; i < 1024; ++i) cnt += (lk[i] < kj) ? 1 : 0;
    atomicAdd(&rank[j], cnt);
}

// ---------------- K4: scatter-gather fused: sb[rank[j]] = offset-box(j) ----------------
__global__ void k_sgather(const float4* __restrict__ boxes4, const int* __restrict__ idxs,
                          const int* __restrict__ rank1, const u32* __restrict__ maxc,
                          float4* __restrict__ sb, float* __restrict__ area, int* __restrict__ order) {
    int j = blockIdx.x * 256 + threadIdx.x;
    if (j >= NBOX) return;
    int r = rank1[j];
    float4 b = boxes4[j];
    float mc1 = __uint_as_float(*maxc) + 1.0f;
    float off = (float)idxs[j] * mc1;
    b.x += off; b.y += off; b.z += off; b.w += off;
    sb[r] = b;
    area[r] = (b.z - b.x) * (b.w - b.y);   // area on OFFSET boxes, exactly like ref
    order[r] = j;
}

// ---------------- K5: sparse overlap mask: emit only nonzero (j, w, word) entries ----------------
// entry.x = word (bit b = over(i=64w+b, j), i<j) ; entry.y = (j<<7)|w
__global__ void k_mask(const float4* __restrict__ sb, const float* __restrict__ area,
                       ulonglong2* __restrict__ ent, u32* __restrict__ cursor) {
    __shared__ float4 ib[64];
    __shared__ float  ia[64];
    int w = blockIdx.x;                       // 0..127
    int j = blockIdx.y * 256 + threadIdx.x;   // 0..8191
    if (threadIdx.x < 64) {
        ib[threadIdx.x] = sb[w * 64 + threadIdx.x];
        ia[threadIdx.x] = area[w * 64 + threadIdx.x];
    }
    __syncthreads();
    if (w * 64 >= j) return;                  // no i<j in this word
    float4 bj = sb[j];
    float  aj = area[j];
    u64 word = 0;
    int nb = min(64, j - w * 64);
    for (int b = 0; b < nb; ++b) {
        float4 bi = ib[b];
        float ltx = fmaxf(bi.x, bj.x), lty = fmaxf(bi.y, bj.y);
        float rbx = fminf(bi.z, bj.z), rby = fminf(bi.w, bj.w);
        float wx = fmaxf(rbx - ltx, 0.0f), wy = fmaxf(rby - lty, 0.0f);
        float inter = wx * wy;
        if (inter > 0.0f) {                   // iou==0 can never exceed thr
            float iou = inter / (ia[b] + aj - inter);   // IEEE f32 div, matches ref
            if (iou > IOU_THR) word |= (1ULL << b);
        }
    }
    if (word) {
        u32 idx = atomicAdd(cursor, 1u);
        if (idx < ENT_CAP) {
            ulonglong2 e;
            e.x = word;
            e.y = (u64)(((u32)j << 7) | (u32)w);
            ent[idx] = e;
        }
    }
}

// ---------------- K6: single-block exact greedy resolve over sparse entries ----------------
__global__ void __launch_bounds__(1024)
k_resolve(const ulonglong2* __restrict__ ent, const u32* __restrict__ cursor,
          const int* __restrict__ order, ulonglong2* __restrict__ sortedE,
          u64* __restrict__ keptF_g, u64* __restrict__ keptO_g,
          u32* __restrict__ wps_g, u32* __restrict__ wpo_g, u32* __restrict__ nkept_g) {
    __shared__ u32 cnt[NW], off[NW], cur[NW];
    __shared__ u64 kw[NW], ko[NW];
    __shared__ u32 wps[NW], wpo[NW];
    __shared__ ulonglong2 sE[ENT_LDS];
    __shared__ u32 s_n, s_fits;

    int t = threadIdx.x;
    if (t < NW) { cnt[t] = 0; cur[t] = 0; ko[t] = 0ULL; }
    if (t == 0) {
        u32 n = *cursor; if (n > ENT_CAP) n = ENT_CAP;
        s_n = n; s_fits = (n <= (u32)ENT_LDS) ? 1u : 0u;
    }
    __syncthreads();
    u32 n = s_n, fits = s_fits;

    // bucket counts by target word v = j>>6
    for (u32 e = t; e < n; e += 1024) {
        u32 meta = (u32)ent[e].y;
        u32 v = (meta >> 7) >> 6;
        atomicAdd(&cnt[v], 1u);
    }
    __syncthreads();
    if (t == 0) { u32 run = 0; for (int v = 0; v < NW; ++v) { off[v] = run; run += cnt[v]; } }
    __syncthreads();
    // scatter into v-sorted array (LDS when it fits, else global)
    for (u32 e = t; e < n; e += 1024) {
        ulonglong2 E = ent[e];
        u32 meta = (u32)E.y;
        u32 v = (meta >> 7) >> 6;
        u32 idx = off[v] + atomicAdd(&cur[v], 1u);
        if (fits) sE[idx] = E; else sortedE[idx] = E;
    }
    __syncthreads();

    // wave 0: sequential sweep over the 128 words — exact greedy
    if (t < 64) {
        int lane = t;
        u32 run = 0;
        for (int v = 0; v < NW; ++v) {
            u32 beg = off[v], num = cnt[v];
            bool supext = false;
            u64 col = 0ULL;
            for (u32 e = 0; e < num; ++e) {
                ulonglong2 E = fits ? sE[beg + e] : sortedE[beg + e];
                u32 meta = (u32)E.y;
                u32 ej = meta >> 7, ew = meta & 127u;
                if ((int)(ej & 63u) == lane) {
                    if ((int)ew == v) col = E.x;                       // intra-word column
                    else supext |= (E.x & kw[ew]) != 0ULL;             // kept earlier word
                }
            }
            // intra-word fixpoint (unique, == sequential greedy; col bits are i<j only)
            u64 k = __ballot(!supext);
            for (int it = 0; it < 64; ++it) {
                bool supin = (col & k) != 0ULL;
                u64 k2 = __ballot(!supext && !supin);
                if (k2 == k) break;
                k = k2;
            }
            if (lane == 0) { kw[v] = k; wps[v] = run; }
            run += __popcll(k);
        }
        if (lane == 0) *nkept_g = run;
    }
    __syncthreads();

    // kept bitmap in ORIGINAL order + word-prefix sums
    for (int r = t; r < NBOX; r += 1024) {
        if ((kw[r >> 6] >> (r & 63)) & 1ULL) {
            int j = order[r];
            atomicOr(&ko[j >> 6], 1ULL << (j & 63));
        }
    }
    __syncthreads();
    if (t == 0) { u32 run = 0; for (int v = 0; v < NW; ++v) { wpo[v] = run; run += __popcll(ko[v]); } }
    __syncthreads();
    if (t < NW) { keptF_g[t] = kw[t]; keptO_g[t] = ko[t]; wps_g[t] = wps[t]; wpo_g[t] = wpo[t]; }
}

// ---------------- K7: final placement via popcount prefix (replaces 2nd sort) ----------------
// kept box: pos = rank among kept in sorted order (score desc, idx asc — same as stable argsort)
// suppressed box (score 0): pos = nkept + rank among suppressed by ORIGINAL index
__global__ void k_out(const float4* __restrict__ boxes4, const float* __restrict__ scores,
                      const int* __restrict__ rank1,
                      const u64* __restrict__ keptF, const u64* __restrict__ keptO,
                      const u32* __restrict__ wps, const u32* __restrict__ wpo,
                      const u32* __restrict__ nkept_p, float* __restrict__ out) {
    int j = blockIdx.x * 256 + threadIdx.x;
    if (j >= NBOX) return;
    int r = rank1[j];
    u64 kwrd = keptF[r >> 6];
    bool kept = (kwrd >> (r & 63)) & 1ULL;
    u32 pos;
    if (kept) {
        pos = wps[r >> 6] + (u32)__popcll(kwrd & ((1ULL << (r & 63)) - 1ULL));
    } else {
        u64 ow = keptO[j >> 6];
        u32 prefO = wpo[j >> 6] + (u32)__popcll(ow & ((1ULL << (j & 63)) - 1ULL));
        pos = *nkept_p + (u32)j - prefO;
    }
    float4 b = boxes4[j];
    float s = kept ? scores[j] : 0.0f;
    out[pos * 5 + 0] = b.x;
    out[pos * 5 + 1] = b.y;
    out[pos * 5 + 2] = b.z;
    out[pos * 5 + 3] = b.w;
    out[pos * 5 + 4] = s;
    out[NBOX * 5 + pos] = (float)j;
}

extern "C" void kernel_launch(void* const* d_in, const int* in_sizes, int n_in,
                              void* d_out, int out_size, void* d_ws, size_t ws_size,
                              hipStream_t stream) {
    const float* boxes  = (const float*)d_in[0];
    const float* scores = (const float*)d_in[1];
    const int*   idxs   = (const int*)d_in[2];
    float* out = (float*)d_out;

    char* w = (char*)d_ws;
    u64*        key1    = (u64*)       (w + 0);         //  65536
    int*        rank1   = (int*)       (w + 65536);     //  32768
    int*        order   = (int*)       (w + 98304);     //  32768
    float4*     sb      = (float4*)    (w + 131072);    // 131072
    float*      area    = (float*)     (w + 262144);    //  32768
    ulonglong2* ent     = (ulonglong2*)(w + 294912);    // 1048576
    ulonglong2* sortedE = (ulonglong2*)(w + 1343488);   // 1048576
    u64*        keptF   = (u64*)       (w + 2392064);   //   1024
    u64*        keptO   = (u64*)       (w + 2393088);   //   1024
    u32*        wps     = (u32*)       (w + 2394112);   //    512
    u32*        wpo     = (u32*)       (w + 2394624);   //    512
    u32*        nkept   = (u32*)       (w + 2395136);   //      4
    u32*        cursor  = (u32*)       (w + 2395140);   //      4
    u32*        maxc    = (u32*)       (w + 2395144);   //      4

    k_init<<<32, 256, 0, stream>>>(scores, key1, rank1, cursor, maxc);
    k_max<<<32, 256, 0, stream>>>(boxes, maxc);
    k_rank<<<256, 256, 0, stream>>>(key1, rank1);
    k_sgather<<<32, 256, 0, stream>>>((const float4*)boxes, idxs, rank1, maxc, sb, area, order);
    dim3 gm(128, 32);
    k_mask<<<gm, 256, 0, stream>>>(sb, area, ent, cursor);
    k_resolve<<<1, 1024, 0, stream>>>(ent, cursor, order, sortedE, keptF, keptO, wps, wpo, nkept);
    k_out<<<32, 256, 0, stream>>>((const float4*)boxes, scores, rank1, keptF, keptO, wps, wpo, nkept, out);
}

// Round 3
// 68.706 us; speedup vs baseline: 2.7972x; 1.4492x over previous
//
#include <hip/hip_runtime.h>
#include <stdint.h>

#define NBOX 8192
#define NW   128            // NBOX/64 words
#define IOU_THR 0.45f
#define ENT_CAP 65536u      // global entry capacity
#define ENT_LDS 2560        // LDS-staged entry capacity (40 KB)

typedef unsigned long long u64;
typedef unsigned int u32;

// ---------------- K1: fused init: sort key1 + grid max(boxes) ----------------
// key = (~bits(score))<<32 | idx : ascending == (score desc, idx asc) == stable argsort(-scores)
// rank1/cursor/maxc are zeroed by hipMemsetAsync before this kernel.
__global__ void k_initmax(const float* __restrict__ scores, const float* __restrict__ boxes,
                          u64* __restrict__ key1, u32* __restrict__ maxc) {
    __shared__ float red[256];
    int j = blockIdx.x * 256 + threadIdx.x;
    if (j < NBOX) {
        u32 u = ~__float_as_uint(scores[j]);
        key1[j] = ((u64)u << 32) | (u32)j;
    }
    float m = 0.0f;                                  // coords >= 0
    for (int i = j; i < NBOX * 4; i += 32 * 256) m = fmaxf(m, boxes[i]);
    red[threadIdx.x] = m;
    __syncthreads();
    for (int s = 128; s > 0; s >>= 1) {
        if (threadIdx.x < s) red[threadIdx.x] = fmaxf(red[threadIdx.x], red[threadIdx.x + s]);
        __syncthreads();
    }
    if (threadIdx.x == 0) atomicMax(maxc, __float_as_uint(red[0]));  // uint cmp == float cmp for +floats
}

// ---------------- K2: rank-count sort: rank[j] += #{i in part : key[i] < key[j]} ----------------
__global__ void k_rank(const u64* __restrict__ key, int* __restrict__ rank) {
    __shared__ u64 lk[1024];
    int jc = blockIdx.x & 31;
    int ip = blockIdx.x >> 5;
    int base = ip * 1024;
    for (int i = threadIdx.x; i < 1024; i += 256) lk[i] = key[base + i];
    __syncthreads();
    int j = jc * 256 + threadIdx.x;
    u64 kj = key[j];
    int cnt = 0;
#pragma unroll 8
    for (int i = 0; i < 1024; ++i) cnt += (lk[i] < kj) ? 1 : 0;
    atomicAdd(&rank[j], cnt);
}

// ---------------- K3: scatter-gather fused: sb[rank[j]] = offset-box(j) ----------------
__global__ void k_sgather(const float4* __restrict__ boxes4, const int* __restrict__ idxs,
                          const int* __restrict__ rank1, const u32* __restrict__ maxc,
                          float4* __restrict__ sb, float* __restrict__ area, int* __restrict__ order) {
    int j = blockIdx.x * 256 + threadIdx.x;
    if (j >= NBOX) return;
    int r = rank1[j];
    float4 b = boxes4[j];
    float mc1 = __uint_as_float(*maxc) + 1.0f;
    float off = (float)idxs[j] * mc1;
    b.x += off; b.y += off; b.z += off; b.w += off;
    sb[r] = b;
    area[r] = (b.z - b.x) * (b.w - b.y);   // area on OFFSET boxes, exactly like ref
    order[r] = j;
}

// ---------------- K4: sparse overlap mask: emit only nonzero (j, w, word) entries ----------------
// entry.x = word (bit b = over(i=64w+b, j), i<j) ; entry.y = (j<<7)|w
__global__ void k_mask(const float4* __restrict__ sb, const float* __restrict__ area,
                       ulonglong2* __restrict__ ent, u32* __restrict__ cursor) {
    __shared__ float4 ib[64];
    __shared__ float  ia[64];
    int w = blockIdx.x;                       // 0..127
    int j = blockIdx.y * 256 + threadIdx.x;   // 0..8191
    if (threadIdx.x < 64) {
        ib[threadIdx.x] = sb[w * 64 + threadIdx.x];
        ia[threadIdx.x] = area[w * 64 + threadIdx.x];
    }
    __syncthreads();
    if (w * 64 >= j) return;                  // no i<j in this word
    float4 bj = sb[j];
    float  aj = area[j];
    u64 word = 0;
    int nb = min(64, j - w * 64);
    for (int b = 0; b < nb; ++b) {
        float4 bi = ib[b];
        float ltx = fmaxf(bi.x, bj.x), lty = fmaxf(bi.y, bj.y);
        float rbx = fminf(bi.z, bj.z), rby = fminf(bi.w, bj.w);
        float wx = fmaxf(rbx - ltx, 0.0f), wy = fmaxf(rby - lty, 0.0f);
        float inter = wx * wy;
        if (inter > 0.0f) {                   // iou==0 can never exceed thr
            float iou = inter / (ia[b] + aj - inter);   // IEEE f32 div, matches ref
            if (iou > IOU_THR) word |= (1ULL << b);
        }
    }
    if (word) {
        u32 idx = atomicAdd(cursor, 1u);
        if (idx < ENT_CAP) {
            ulonglong2 e;
            e.x = word;
            e.y = (u64)(((u32)j << 7) | (u32)w);
            ent[idx] = e;
        }
    }
}

// ---------------- K5: single-block parallel Jacobi fixpoint (exact greedy) ----------------
// kept[j] = !exists i<j : kept[i] && over(i,j). Unique fixpoint; Jacobi iterate
// until stable — stability certifies the exact greedy answer.
__global__ void __launch_bounds__(256)
k_resolve(const ulonglong2* __restrict__ ent, const u32* __restrict__ cursor,
          const int* __restrict__ order,
          u64* __restrict__ keptF_g, u64* __restrict__ keptO_g,
          u32* __restrict__ wps_g, u32* __restrict__ wpo_g, u32* __restrict__ nkept_g) {
    __shared__ u64 kw[NW], sup[NW], ko[NW];
    __shared__ ulonglong2 sE[ENT_LDS];
    __shared__ u32 s_n;
    __shared__ int chg;

    int t = threadIdx.x;
    if (t == 0) { u32 nn = *cursor; if (nn > ENT_CAP) nn = ENT_CAP; s_n = nn; }
    if (t < NW) { kw[t] = ~0ULL; ko[t] = 0ULL; }
    __syncthreads();
    u32 n = s_n;
    bool fits = (n <= (u32)ENT_LDS);
    if (fits) for (u32 e = t; e < n; e += 256) sE[e] = ent[e];
    // (staging completes before first use: sync A below)

    for (int iter = 0; iter < NBOX; ++iter) {
        if (t < NW) sup[t] = 0ULL;
        if (t == 0) chg = 0;
        __syncthreads();                               // A
        for (u32 e = t; e < n; e += 256) {
            ulonglong2 E = fits ? sE[e] : ent[e];
            u32 meta = (u32)E.y;
            u32 ej = meta >> 7, ew = meta & 127u;
            if (E.x & kw[ew]) atomicOr(&sup[ej >> 6], 1ULL << (ej & 63u));
        }
        __syncthreads();                               // B
        if (t < NW) {
            u64 nk = ~sup[t];
            if (nk != kw[t]) { kw[t] = nk; chg = 1; }  // benign same-value race
        }
        __syncthreads();                               // C
        int done = !chg;
        __syncthreads();                               // D: all read chg before next clear
        if (done) break;
    }

    // kept bitmap in ORIGINAL order
    for (int r = t; r < NBOX; r += 256) {
        if ((kw[r >> 6] >> (r & 63)) & 1ULL) {
            int j = order[r];
            atomicOr(&ko[j >> 6], 1ULL << (j & 63));
        }
    }
    __syncthreads();
    if (t < NW) { keptF_g[t] = kw[t]; keptO_g[t] = ko[t]; }
    // wave 0: word-prefix popcount scans via shuffles (no syncs needed)
    if (t < 64) {
        int l = t;
        u32 a0 = (u32)__popcll(kw[2 * l]), a1 = (u32)__popcll(kw[2 * l + 1]);
        u32 s = a0 + a1;
        for (int d = 1; d < 64; d <<= 1) { u32 v = __shfl_up(s, d, 64); if (l >= d) s += v; }
        u32 excl = s - a0 - a1;
        wps_g[2 * l] = excl; wps_g[2 * l + 1] = excl + a0;
        if (l == 63) *nkept_g = s;
        u32 b0 = (u32)__popcll(ko[2 * l]), b1 = (u32)__popcll(ko[2 * l + 1]);
        u32 so = b0 + b1;
        for (int d = 1; d < 64; d <<= 1) { u32 v = __shfl_up(so, d, 64); if (l >= d) so += v; }
        u32 exclo = so - b0 - b1;
        wpo_g[2 * l] = exclo; wpo_g[2 * l + 1] = exclo + b0;
    }
}

// ---------------- K6: final placement via popcount prefix (replaces 2nd sort) ----------------
// kept box: pos = rank among kept in sorted order (score desc, idx asc — stable argsort)
// suppressed box (score 0): pos = nkept + rank among suppressed by ORIGINAL index
__global__ void k_out(const float4* __restrict__ boxes4, const float* __restrict__ scores,
                      const int* __restrict__ rank1,
                      const u64* __restrict__ keptF, const u64* __restrict__ keptO,
                      const u32* __restrict__ wps, const u32* __restrict__ wpo,
                      const u32* __restrict__ nkept_p, float* __restrict__ out) {
    int j = blockIdx.x * 256 + threadIdx.x;
    if (j >= NBOX) return;
    int r = rank1[j];
    u64 kwrd = keptF[r >> 6];
    bool kept = (kwrd >> (r & 63)) & 1ULL;
    u32 pos;
    if (kept) {
        pos = wps[r >> 6] + (u32)__popcll(kwrd & ((1ULL << (r & 63)) - 1ULL));
    } else {
        u64 ow = keptO[j >> 6];
        u32 prefO = wpo[j >> 6] + (u32)__popcll(ow & ((1ULL << (j & 63)) - 1ULL));
        pos = *nkept_p + (u32)j - prefO;
    }
    float4 b = boxes4[j];
    float s = kept ? scores[j] : 0.0f;
    out[pos * 5 + 0] = b.x;
    out[pos * 5 + 1] = b.y;
    out[pos * 5 + 2] = b.z;
    out[pos * 5 + 3] = b.w;
    out[pos * 5 + 4] = s;
    out[NBOX * 5 + pos] = (float)j;
}

extern "C" void kernel_launch(void* const* d_in, const int* in_sizes, int n_in,
                              void* d_out, int out_size, void* d_ws, size_t ws_size,
                              hipStream_t stream) {
    const float* boxes  = (const float*)d_in[0];
    const float* scores = (const float*)d_in[1];
    const int*   idxs   = (const int*)d_in[2];
    float* out = (float*)d_out;

    char* w = (char*)d_ws;
    u64*        key1    = (u64*)       (w + 0);         //  65536
    int*        rank1   = (int*)       (w + 65536);     //  32768
    u32*        cursor  = (u32*)       (w + 98304);     //      4
    u32*        maxc    = (u32*)       (w + 98308);     //      4
    int*        order   = (int*)       (w + 98320);     //  32768
    float4*     sb      = (float4*)    (w + 131088);    // 131072 (16B aligned)
    float*      area    = (float*)     (w + 262160);    //  32768
    ulonglong2* ent     = (ulonglong2*)(w + 294928);    // 1048576 (16B aligned)
    u64*        keptF   = (u64*)       (w + 1343504);   //   1024
    u64*        keptO   = (u64*)       (w + 1344528);   //   1024
    u32*        wps     = (u32*)       (w + 1345552);   //    512
    u32*        wpo     = (u32*)       (w + 1346064);   //    512
    u32*        nkept   = (u32*)       (w + 1346576);   //      4

    // zero rank1 + cursor + maxc in one shot (graph-capturable memset node)
    hipMemsetAsync((void*)rank1, 0, 32768 + 8, stream);

    k_initmax<<<32, 256, 0, stream>>>(scores, boxes, key1, maxc);
    k_rank<<<256, 256, 0, stream>>>(key1, rank1);
    k_sgather<<<32, 256, 0, stream>>>((const float4*)boxes, idxs, rank1, maxc, sb, area, order);
    dim3 gm(128, 32);
    k_mask<<<gm, 256, 0, stream>>>(sb, area, ent, cursor);
    k_resolve<<<1, 256, 0, stream>>>(ent, cursor, order, keptF, keptO, wps, wpo, nkept);
    k_out<<<32, 256, 0, stream>>>((const float4*)boxes, scores, rank1, keptF, keptO, wps, wpo, nkept, out);
}

// Round 4
// 63.974 us; speedup vs baseline: 3.0042x; 1.0740x over previous
//
#include <hip/hip_runtime.h>
#include <stdint.h>

#define NBOX 8192
#define NW   128            // NBOX/64 words
#define IOU_THR 0.45f
#define ENT_CAP 65536u      // global entry capacity
#define ENT_LDS 2560        // LDS-staged entry capacity (40 KB)

typedef unsigned long long u64;
typedef unsigned int u32;

// ---------------- K1: fused init: key1 + rank1/cursor zero + per-block box max ----------------
// key = (~bits(score))<<32 | idx : ascending == (score desc, idx asc) == stable argsort(-scores)
__global__ void k_initmax(const float* __restrict__ scores, const float* __restrict__ boxes,
                          u64* __restrict__ key1, int* __restrict__ rank1,
                          u32* __restrict__ cursor, float* __restrict__ blockmax) {
    __shared__ float red[256];
    int j = blockIdx.x * 256 + threadIdx.x;
    if (j < NBOX) {
        rank1[j] = 0;
        u32 u = ~__float_as_uint(scores[j]);
        key1[j] = ((u64)u << 32) | (u32)j;
    }
    if (j == 0) *cursor = 0u;
    float m = 0.0f;                                  // coords >= 0
    for (int i = j; i < NBOX * 4; i += 32 * 256) m = fmaxf(m, boxes[i]);
    red[threadIdx.x] = m;
    __syncthreads();
    for (int s = 128; s > 0; s >>= 1) {
        if (threadIdx.x < s) red[threadIdx.x] = fmaxf(red[threadIdx.x], red[threadIdx.x + s]);
        __syncthreads();
    }
    if (threadIdx.x == 0) blockmax[blockIdx.x] = red[0];   // plain store, no init needed
}

// ---------------- K2: rank-count sort: rank[j] += #{i in part : key[i] < key[j]} ----------------
__global__ void k_rank(const u64* __restrict__ key, int* __restrict__ rank) {
    __shared__ u64 lk[1024];
    int jc = blockIdx.x & 31;
    int ip = blockIdx.x >> 5;
    int base = ip * 1024;
    for (int i = threadIdx.x; i < 1024; i += 256) lk[i] = key[base + i];
    __syncthreads();
    int j = jc * 256 + threadIdx.x;
    u64 kj = key[j];
    int cnt = 0;
#pragma unroll 8
    for (int i = 0; i < 1024; ++i) cnt += (lk[i] < kj) ? 1 : 0;
    atomicAdd(&rank[j], cnt);
}

// ---------------- K3: scatter-gather fused: sb[rank[j]] = offset-box(j) ----------------
__global__ void k_sgather(const float4* __restrict__ boxes4, const int* __restrict__ idxs,
                          const int* __restrict__ rank1, const float* __restrict__ blockmax,
                          float4* __restrict__ sb, float* __restrict__ area, int* __restrict__ order) {
    __shared__ float red[32];
    if (threadIdx.x < 32) red[threadIdx.x] = blockmax[threadIdx.x];
    __syncthreads();
    if (threadIdx.x < 16) red[threadIdx.x] = fmaxf(red[threadIdx.x], red[threadIdx.x + 16]);
    __syncthreads();
    if (threadIdx.x < 8) red[threadIdx.x] = fmaxf(red[threadIdx.x], red[threadIdx.x + 8]);
    __syncthreads();
    if (threadIdx.x < 4) red[threadIdx.x] = fmaxf(red[threadIdx.x], red[threadIdx.x + 4]);
    __syncthreads();
    if (threadIdx.x < 2) red[threadIdx.x] = fmaxf(red[threadIdx.x], red[threadIdx.x + 2]);
    __syncthreads();
    if (threadIdx.x < 1) red[0] = fmaxf(red[0], red[1]);
    __syncthreads();
    float mc1 = red[0] + 1.0f;

    int j = blockIdx.x * 256 + threadIdx.x;
    if (j >= NBOX) return;
    int r = rank1[j];
    float4 b = boxes4[j];
    float off = (float)idxs[j] * mc1;
    b.x += off; b.y += off; b.z += off; b.w += off;
    sb[r] = b;
    area[r] = (b.z - b.x) * (b.w - b.y);   // area on OFFSET boxes, exactly like ref
    order[r] = j;
}

// ---------------- K4: sparse overlap mask: emit only nonzero (j, w, word) entries ----------------
// entry.x = word (bit b = over(i=64w+b, j), i<j) ; entry.y = (j<<7)|w
__global__ void k_mask(const float4* __restrict__ sb, const float* __restrict__ area,
                       ulonglong2* __restrict__ ent, u32* __restrict__ cursor) {
    __shared__ float4 ib[64];
    __shared__ float  ia[64];
    int w = blockIdx.x;                       // 0..127
    int j = blockIdx.y * 256 + threadIdx.x;   // 0..8191
    if (threadIdx.x < 64) {
        ib[threadIdx.x] = sb[w * 64 + threadIdx.x];
        ia[threadIdx.x] = area[w * 64 + threadIdx.x];
    }
    __syncthreads();
    if (w * 64 >= j) return;                  // no i<j in this word
    float4 bj = sb[j];
    float  aj = area[j];
    u64 word = 0;
    int nb = min(64, j - w * 64);
    for (int b = 0; b < nb; ++b) {
        float4 bi = ib[b];
        float ltx = fmaxf(bi.x, bj.x), lty = fmaxf(bi.y, bj.y);
        float rbx = fminf(bi.z, bj.z), rby = fminf(bi.w, bj.w);
        float wx = fmaxf(rbx - ltx, 0.0f), wy = fmaxf(rby - lty, 0.0f);
        float inter = wx * wy;
        if (inter > 0.0f) {                   // iou==0 can never exceed thr
            float iou = inter / (ia[b] + aj - inter);   // IEEE f32 div, matches ref
            if (iou > IOU_THR) word |= (1ULL << b);
        }
    }
    if (word) {
        u32 idx = atomicAdd(cursor, 1u);
        if (idx < ENT_CAP) {
            ulonglong2 e;
            e.x = word;
            e.y = (u64)(((u32)j << 7) | (u32)w);
            ent[idx] = e;
        }
    }
}

// ---------------- K5: single-block parallel Jacobi fixpoint (exact greedy) ----------------
// kept[j] = !exists i<j : kept[i] && over(i,j). Unique fixpoint; Jacobi iterate
// until stable — stability certifies the exact greedy answer.
__global__ void __launch_bounds__(256)
k_resolve(const ulonglong2* __restrict__ ent, const u32* __restrict__ cursor,
          const int* __restrict__ order,
          u64* __restrict__ keptF_g, u64* __restrict__ keptO_g,
          u32* __restrict__ wps_g, u32* __restrict__ wpo_g, u32* __restrict__ nkept_g) {
    __shared__ u64 kw[NW], sup[NW], ko[NW];
    __shared__ ulonglong2 sE[ENT_LDS];
    __shared__ u32 s_n;
    __shared__ int chg;

    int t = threadIdx.x;
    if (t == 0) { u32 nn = *cursor; if (nn > ENT_CAP) nn = ENT_CAP; s_n = nn; }
    if (t < NW) { kw[t] = ~0ULL; ko[t] = 0ULL; }
    __syncthreads();
    u32 n = s_n;
    bool fits = (n <= (u32)ENT_LDS);
    if (fits) for (u32 e = t; e < n; e += 256) sE[e] = ent[e];
    // (staging completes before first use: sync A below)

    for (int iter = 0; iter < NBOX; ++iter) {
        if (t < NW) sup[t] = 0ULL;
        if (t == 0) chg = 0;
        __syncthreads();                               // A
        for (u32 e = t; e < n; e += 256) {
            ulonglong2 E = fits ? sE[e] : ent[e];
            u32 meta = (u32)E.y;
            u32 ej = meta >> 7, ew = meta & 127u;
            if (E.x & kw[ew]) atomicOr(&sup[ej >> 6], 1ULL << (ej & 63u));
        }
        __syncthreads();                               // B
        if (t < NW) {
            u64 nk = ~sup[t];
            if (nk != kw[t]) { kw[t] = nk; chg = 1; }  // benign same-value race
        }
        __syncthreads();                               // C
        int done = !chg;
        __syncthreads();                               // D: all read chg before next clear
        if (done) break;
    }

    // kept bitmap in ORIGINAL order
    for (int r = t; r < NBOX; r += 256) {
        if ((kw[r >> 6] >> (r & 63)) & 1ULL) {
            int j = order[r];
            atomicOr(&ko[j >> 6], 1ULL << (j & 63));
        }
    }
    __syncthreads();
    if (t < NW) { keptF_g[t] = kw[t]; keptO_g[t] = ko[t]; }
    // wave 0: word-prefix popcount scans via shuffles (no syncs needed)
    if (t < 64) {
        int l = t;
        u32 a0 = (u32)__popcll(kw[2 * l]), a1 = (u32)__popcll(kw[2 * l + 1]);
        u32 s = a0 + a1;
        for (int d = 1; d < 64; d <<= 1) { u32 v = __shfl_up(s, d, 64); if (l >= d) s += v; }
        u32 excl = s - a0 - a1;
        wps_g[2 * l] = excl; wps_g[2 * l + 1] = excl + a0;
        if (l == 63) *nkept_g = s;
        u32 b0 = (u32)__popcll(ko[2 * l]), b1 = (u32)__popcll(ko[2 * l + 1]);
        u32 so = b0 + b1;
        for (int d = 1; d < 64; d <<= 1) { u32 v = __shfl_up(so, d, 64); if (l >= d) so += v; }
        u32 exclo = so - b0 - b1;
        wpo_g[2 * l] = exclo; wpo_g[2 * l + 1] = exclo + b0;
    }
}

// ---------------- K6: final placement via popcount prefix (replaces 2nd sort) ----------------
// kept box: pos = rank among kept in sorted order (score desc, idx asc — stable argsort)
// suppressed box (score 0): pos = nkept + rank among suppressed by ORIGINAL index
__global__ void k_out(const float4* __restrict__ boxes4, const float* __restrict__ scores,
                      const int* __restrict__ rank1,
                      const u64* __restrict__ keptF, const u64* __restrict__ keptO,
                      const u32* __restrict__ wps, const u32* __restrict__ wpo,
                      const u32* __restrict__ nkept_p, float* __restrict__ out) {
    int j = blockIdx.x * 256 + threadIdx.x;
    if (j >= NBOX) return;
    int r = rank1[j];
    u64 kwrd = keptF[r >> 6];
    bool kept = (kwrd >> (r & 63)) & 1ULL;
    u32 pos;
    if (kept) {
        pos = wps[r >> 6] + (u32)__popcll(kwrd & ((1ULL << (r & 63)) - 1ULL));
    } else {
        u64 ow = keptO[j >> 6];
        u32 prefO = wpo[j >> 6] + (u32)__popcll(ow & ((1ULL << (j & 63)) - 1ULL));
        pos = *nkept_p + (u32)j - prefO;
    }
    float4 b = boxes4[j];
    float s = kept ? scores[j] : 0.0f;
    out[pos * 5 + 0] = b.x;
    out[pos * 5 + 1] = b.y;
    out[pos * 5 + 2] = b.z;
    out[pos * 5 + 3] = b.w;
    out[pos * 5 + 4] = s;
    out[NBOX * 5 + pos] = (float)j;
}

extern "C" void kernel_launch(void* const* d_in, const int* in_sizes, int n_in,
                              void* d_out, int out_size, void* d_ws, size_t ws_size,
                              hipStream_t stream) {
    const float* boxes  = (const float*)d_in[0];
    const float* scores = (const float*)d_in[1];
    const int*   idxs   = (const int*)d_in[2];
    float* out = (float*)d_out;

    char* w = (char*)d_ws;
    u64*        key1     = (u64*)       (w + 0);         //  65536
    int*        rank1    = (int*)       (w + 65536);     //  32768
    u32*        cursor   = (u32*)       (w + 98304);     //      4
    float*      blockmax = (float*)     (w + 98308);     //    128
    int*        order    = (int*)       (w + 98448);     //  32768
    float4*     sb       = (float4*)    (w + 131216);    // 131072 (16B aligned)
    float*      area     = (float*)     (w + 262288);    //  32768
    ulonglong2* ent      = (ulonglong2*)(w + 295056);    // 1048576 (16B aligned)
    u64*        keptF    = (u64*)       (w + 1343632);   //   1024
    u64*        keptO    = (u64*)       (w + 1344656);   //   1024
    u32*        wps      = (u32*)       (w + 1345680);   //    512
    u32*        wpo      = (u32*)       (w + 1346192);   //    512
    u32*        nkept    = (u32*)       (w + 1346704);   //      4

    k_initmax<<<32, 256, 0, stream>>>(scores, boxes, key1, rank1, cursor, blockmax);
    k_rank<<<256, 256, 0, stream>>>(key1, rank1);
    k_sgather<<<32, 256, 0, stream>>>((const float4*)boxes, idxs, rank1, blockmax, sb, area, order);
    dim3 gm(128, 32);
    k_mask<<<gm, 256, 0, stream>>>(sb, area, ent, cursor);
    k_resolve<<<1, 256, 0, stream>>>(ent, cursor, order, keptF, keptO, wps, wpo, nkept);
    k_out<<<32, 256, 0, stream>>>((const float4*)boxes, scores, rank1, keptF, keptO, wps, wpo, nkept, out);
}